// Round 10
// baseline (1221.884 us; speedup 1.0000x reference)
//
#include <hip/hip_runtime.h>
#include <hip/hip_bf16.h>

#define N_NODES 100000
#define N_EDGES 1600000
#define IN_C 512
#define HID_C 256
#define OUT_C 64
#define K_ITERS 10
#define ALPHA 0.1f

typedef float f32x4 __attribute__((ext_vector_type(4)));
typedef _Float16 f16;
typedef _Float16 f16x4 __attribute__((ext_vector_type(4)));
typedef _Float16 f16x8 __attribute__((ext_vector_type(8)));

#define MFMA16(a, b, c) __builtin_amdgcn_mfma_f32_16x16x32_f16((a), (b), (c), 0, 0, 0)

__device__ __forceinline__ void gload16(const void* g, void* l) {
    __builtin_amdgcn_global_load_lds(
        (const __attribute__((address_space(1))) unsigned int*)g,
        (__attribute__((address_space(3))) unsigned int*)l, 16, 0, 0);
}

// ---------------------------------------------------------------------------
// CSR build kernels
// ---------------------------------------------------------------------------
__global__ void k_count(const int* __restrict__ ei, int* __restrict__ cnt, int E) {
    int e = blockIdx.x * blockDim.x + threadIdx.x;
    if (e < E) atomicAdd(&cnt[ei[E + e]], 1);
}

__global__ void k_dinv(const int* __restrict__ cnt, float* __restrict__ dinv, int n) {
    int i = blockIdx.x * blockDim.x + threadIdx.x;
    if (i < n) dinv[i] = rsqrtf((float)cnt[i] + 1.0f);  // +1 for self-loop
}

// ---------------------------------------------------------------------------
// Two-level scan: 1024 elems/block (256 thr x 4).
// ---------------------------------------------------------------------------
#define SCB 1024
__global__ __launch_bounds__(256) void k_scan1(const int* __restrict__ cnt,
                                               int* __restrict__ bsum, int n) {
    __shared__ int s[256];
    int b = blockIdx.x, t = threadIdx.x;
    int base = b * SCB + t * 4;
    int local = 0;
#pragma unroll
    for (int j = 0; j < 4; ++j) {
        int i = base + j;
        if (i < n) local += cnt[i];
    }
    s[t] = local;
    __syncthreads();
    for (int off = 1; off < 256; off <<= 1) {
        int u = (t >= off) ? s[t - off] : 0;
        __syncthreads();
        s[t] += u;
        __syncthreads();
    }
    if (t == 255) bsum[b] = s[255];
}

__global__ __launch_bounds__(128) void k_scan2(const int* __restrict__ bsum,
                                               int* __restrict__ boff, int G,
                                               int* __restrict__ row_ptr, int n, int total) {
    __shared__ int s[128];
    int t = threadIdx.x;
    int v = (t < G) ? bsum[t] : 0;
    s[t] = v;
    __syncthreads();
    for (int off = 1; off < 128; off <<= 1) {
        int u = (t >= off) ? s[t - off] : 0;
        __syncthreads();
        s[t] += u;
        __syncthreads();
    }
    if (t < G) boff[t] = s[t] - v;
    if (t == 0) row_ptr[n] = total;
}

__global__ __launch_bounds__(256) void k_scan3(const int* __restrict__ cnt,
                                               const int* __restrict__ boff,
                                               int* __restrict__ row_ptr,
                                               int* __restrict__ cursor, int n) {
    __shared__ int s[256];
    int b = blockIdx.x, t = threadIdx.x;
    int base = b * SCB + t * 4;
    int c4[4];
    int local = 0;
#pragma unroll
    for (int j = 0; j < 4; ++j) {
        int i = base + j;
        c4[j] = (i < n) ? cnt[i] : 0;
        local += c4[j];
    }
    s[t] = local;
    __syncthreads();
    for (int off = 1; off < 256; off <<= 1) {
        int u = (t >= off) ? s[t - off] : 0;
        __syncthreads();
        s[t] += u;
        __syncthreads();
    }
    int run = boff[b] + s[t] - local;
#pragma unroll
    for (int j = 0; j < 4; ++j) {
        int i = base + j;
        if (i < n) {
            row_ptr[i] = run;
            cursor[i] = run;
            run += c4[j];
        }
    }
}

// k_fill writes packed (src, weight) metadata: one 8B load per edge later.
__global__ void k_fill(const int* __restrict__ ei, const float* __restrict__ dinv,
                       int* __restrict__ cursor, int2* __restrict__ csr_pack, int E) {
    int e = blockIdx.x * blockDim.x + threadIdx.x;
    if (e < E) {
        int s = ei[e];
        int d = ei[E + e];
        int pos = atomicAdd(&cursor[d], 1);
        csr_pack[pos] = make_int2(s, __float_as_int(dinv[s] * dinv[d]));
    }
}

// ---------------------------------------------------------------------------
// Degree counting-sort (256 buckets): perm[] lists nodes in ascending-degree
// order so the 8 nodes sharing a prop wave have near-equal degree (kills the
// wave-max batch waste). Order within a bucket is arbitrary.
// ---------------------------------------------------------------------------
__global__ void k_hist(const int* __restrict__ cnt, int* __restrict__ hist, int n) {
    int i = blockIdx.x * blockDim.x + threadIdx.x;
    if (i < n) atomicAdd(&hist[min(cnt[i], 255)], 1);
}

__global__ __launch_bounds__(256) void k_hscan(const int* __restrict__ hist,
                                               int* __restrict__ hcur) {
    __shared__ int s[256];
    int t = threadIdx.x;
    int v = hist[t];
    s[t] = v;
    __syncthreads();
    for (int off = 1; off < 256; off <<= 1) {
        int u = (t >= off) ? s[t - off] : 0;
        __syncthreads();
        s[t] += u;
        __syncthreads();
    }
    hcur[t] = s[t] - v;  // exclusive prefix
}

__global__ void k_perm(const int* __restrict__ cnt, int* __restrict__ hcur,
                       int* __restrict__ perm, int n) {
    int i = blockIdx.x * blockDim.x + threadIdx.x;
    if (i < n) {
        int b = min(cnt[i], 255);
        int pos = atomicAdd(&hcur[b], 1);
        perm[pos] = i;
    }
}

// ---------------------------------------------------------------------------
// Weight cast: f32 -> f16 (single precision term; rel err ~4.9e-4).
// ---------------------------------------------------------------------------
__global__ void k_cast(const float* __restrict__ in, f16* __restrict__ out, int n) {
    int i = blockIdx.x * blockDim.x + threadIdx.x;
    if (i < n) out[i] = (f16)in[i];
}

// ---------------------------------------------------------------------------
// Fused f16 MFMA MLP v5.
// vs v4: x software-pipelined one k-step ahead. The two float4 x-loads for
// step ks+1 are ISSUED right after barrier #1 of step ks and consumed next
// step, so the vmcnt(0) drain at barrier #2 finds them (mostly) landed --
// removing the per-step exposed HBM latency that kept both pipes <11% busy.
// ---------------------------------------------------------------------------
__global__ __launch_bounds__(256, 4) void k_mlp2(
    const float* __restrict__ x,
    const f16* __restrict__ w1h,
    const float* __restrict__ b1,
    const f16* __restrict__ w2h,
    const float* __restrict__ b2,
    f16* __restrict__ h016, f16* __restrict__ hcur16, int n) {
    __shared__ __align__(16) union {
        struct {
            f16 Ah[64 * 40];   // 5 KB, rows padded to 40
            f16 Bh[256 * 32];  // 16 KB, chunk-swizzled
        } p1;
        struct {
            f16 Hh[64 * 264];  // 33.8 KB, rows padded to 264
        } p2;
    } sm;

    const int tid = threadIdx.x;
    const int l = tid & 63;
    const int w = tid >> 6;
    const int lr = l & 15;
    const int kg = l >> 4;
    const int row0 = blockIdx.x * 64;

    // A-staging coordinates (loop-invariant)
    const int r0 = tid >> 3, kk0 = (tid & 7) * 4;
    const int r1 = (tid + 256) >> 3, kk1 = (tid & 7) * 4;
    int gr0 = row0 + r0; if (gr0 >= n) gr0 = n - 1;
    int gr1 = row0 + r1; if (gr1 >= n) gr1 = n - 1;
    const float* xp0 = &x[(size_t)gr0 * IN_C + kk0];
    const float* xp1 = &x[(size_t)gr1 * IN_C + kk1];

    f32x4 acc[4][4];
#pragma unroll
    for (int m = 0; m < 4; ++m)
#pragma unroll
        for (int nf = 0; nf < 4; ++nf) acc[m][nf] = (f32x4)0.0f;

    // preload x for ks=0
    float4 xv0 = *(const float4*)xp0;
    float4 xv1 = *(const float4*)xp1;

    for (int ks = 0; ks < 16; ++ks) {
        const int k0 = ks * 32;
        // ---- stage B (w1 f16 tile, chunk-swizzled source) ----
#pragma unroll
        for (int i = 0; i < 4; ++i) {
            int slot = tid + 256 * i;
            int row = slot >> 2;
            int kc = (slot & 3) ^ ((row >> 1) & 3);
            size_t goff = (size_t)row * IN_C + k0 + kc * 8;
            int sbase = (w * 64 + 256 * i) * 8;
            gload16(w1h + goff, &sm.p1.Bh[sbase]);
        }
        // ---- stage A from prefetched regs (f32 -> f16) ----
        {
            f16x4 h4;
            h4.x = (f16)xv0.x; h4.y = (f16)xv0.y; h4.z = (f16)xv0.z; h4.w = (f16)xv0.w;
            *(f16x4*)&sm.p1.Ah[r0 * 40 + kk0] = h4;
            h4.x = (f16)xv1.x; h4.y = (f16)xv1.y; h4.z = (f16)xv1.z; h4.w = (f16)xv1.w;
            *(f16x4*)&sm.p1.Ah[r1 * 40 + kk1] = h4;
        }
        __syncthreads();

        // ---- prefetch next step's x during the MFMA phase ----
        if (ks < 15) {
            xv0 = *(const float4*)(xp0 + k0 + 32);
            xv1 = *(const float4*)(xp1 + k0 + 32);
        }

        f16x8 ah[4], bh[4];
#pragma unroll
        for (int m = 0; m < 4; ++m)
            ah[m] = *(const f16x8*)&sm.p1.Ah[(m * 16 + lr) * 40 + kg * 8];
#pragma unroll
        for (int nf = 0; nf < 4; ++nf) {
            int row = w * 64 + nf * 16 + lr;
            int kc = kg ^ ((row >> 1) & 3);
            bh[nf] = *(const f16x8*)&sm.p1.Bh[row * 32 + kc * 8];
        }
#pragma unroll
        for (int m = 0; m < 4; ++m)
#pragma unroll
            for (int nf = 0; nf < 4; ++nf)
                acc[m][nf] = MFMA16(ah[m], bh[nf], acc[m][nf]);
        __syncthreads();
    }

    // ---- epilogue 1: bias + relu -> f16 H1 in LDS ----
#pragma unroll
    for (int m = 0; m < 4; ++m)
#pragma unroll
        for (int nf = 0; nf < 4; ++nf) {
            int col = w * 64 + nf * 16 + lr;
            float bb = b1[col];
#pragma unroll
            for (int r = 0; r < 4; ++r) {
                int row = m * 16 + kg * 4 + r;
                float hv = acc[m][nf][r] + bb;
                hv = fmaxf(hv, 0.0f);
                sm.p2.Hh[row * 264 + col] = (f16)hv;
            }
        }
    __syncthreads();

    // ---- phase 2: out[64][64] = H1 @ W2^T + b2 ----
    f32x4 acc2[4];
#pragma unroll
    for (int m = 0; m < 4; ++m) acc2[m] = (f32x4)0.0f;
    const int col2 = w * 16 + lr;

#pragma unroll
    for (int k0 = 0; k0 < HID_C; k0 += 32) {
        f16x8 b2h = *(const f16x8*)&w2h[(size_t)col2 * HID_C + k0 + kg * 8];
#pragma unroll
        for (int m = 0; m < 4; ++m) {
            f16x8 a2h = *(const f16x8*)&sm.p2.Hh[(m * 16 + lr) * 264 + k0 + kg * 8];
            acc2[m] = MFMA16(a2h, b2h, acc2[m]);
        }
    }

    float bb2 = b2[col2];
#pragma unroll
    for (int m = 0; m < 4; ++m)
#pragma unroll
        for (int r = 0; r < 4; ++r) {
            int grow = row0 + m * 16 + kg * 4 + r;
            if (grow < n) {
                float vv = acc2[m][r] + bb2;
                size_t idx = (size_t)grow * OUT_C + col2;
                h016[idx] = (f16)vv;
                hcur16[idx] = (f16)vv;
            }
        }
}

// ---------------------------------------------------------------------------
// fp16 propagation v6: v5 structure (8 nodes/wave, 8 lanes x f16x8 per node)
// + degree-sorted node assignment via perm[]: the 8 nodes in a wave have
// near-equal degree, so nb(max) ~ nb(mean) and batch waste vanishes.
// Arithmetic per node is unchanged (same CSR range, same j order).
// ---------------------------------------------------------------------------
__global__ __launch_bounds__(256) void k_prop16(const f16* __restrict__ hin,
                                                const f16* __restrict__ h016,
                                                f16* __restrict__ hout,
                                                float* __restrict__ dout,
                                                const int* __restrict__ row_ptr,
                                                const int2* __restrict__ csr_pack,
                                                const float* __restrict__ dinv,
                                                const int* __restrict__ perm,
                                                int n, int final_iter) {
    const int gwave = (blockIdx.x * blockDim.x + threadIdx.x) >> 6;
    const int lane = threadIdx.x & 63;
    const int g = lane >> 3;   // group 0..7 (node within wave)
    const int cl = lane & 7;   // channel octet: channels 8cl..8cl+7

    int sp = gwave * 8 + g;
    bool node_valid = sp < n;
    int node = perm[node_valid ? sp : (n - 1)];

    int e0 = row_ptr[node], e1 = row_ptr[node + 1];
    int nb = (e1 - e0 + 7) >> 3;
    // wave-max over the 8 groups (group id = lane bits 3..5)
    nb = max(nb, __shfl_xor(nb, 8));
    nb = max(nb, __shfl_xor(nb, 16));
    nb = max(nb, __shfl_xor(nb, 32));

    float a[8];
#pragma unroll
    for (int q = 0; q < 8; ++q) a[q] = 0.0f;
    const int gbase = g * 8;

    for (int b = 0; b < nb; ++b) {
        int mbase = e0 + b * 8;
        int midx = min(mbase + cl, N_EDGES - 1);
        int2 meta = csr_pack[midx];
#pragma unroll
        for (int j = 0; j < 8; ++j) {
            int s = __shfl(meta.x, gbase + j);
            float wv = __int_as_float(__shfl(meta.y, gbase + j));
            if (mbase + j < e1) {  // uniform within group
                f16x8 v = *(const f16x8*)&hin[(size_t)s * OUT_C + cl * 8];
#pragma unroll
                for (int q = 0; q < 8; ++q) a[q] += wv * (float)v[q];
            }
        }
    }

    float dv = dinv[node];
    float d2 = dv * dv;
    size_t idx = (size_t)node * OUT_C + cl * 8;
    f16x8 sv = *(const f16x8*)&hin[idx];
    f16x8 h0v = *(const f16x8*)&h016[idx];
    float r[8];
#pragma unroll
    for (int q = 0; q < 8; ++q)
        r[q] = (1.0f - ALPHA) * (a[q] + d2 * (float)sv[q]) + ALPHA * (float)h0v[q];

    if (node_valid) {
        f16x8 o;
#pragma unroll
        for (int q = 0; q < 8; ++q) o[q] = (f16)r[q];
        *(f16x8*)&hout[idx] = o;
        if (final_iter) {
            float4 o0 = make_float4(r[0], r[1], r[2], r[3]);
            float4 o1 = make_float4(r[4], r[5], r[6], r[7]);
            *(float4*)&dout[idx] = o0;
            *(float4*)&dout[idx + 4] = o1;
        }
    }
}

// ---------------------------------------------------------------------------
extern "C" void kernel_launch(void* const* d_in, const int* in_sizes, int n_in,
                              void* d_out, int out_size, void* d_ws, size_t ws_size,
                              hipStream_t stream) {
    const float* x  = (const float*)d_in[0];
    const int*   ei = (const int*)d_in[1];
    const float* w1 = (const float*)d_in[2];
    const float* b1 = (const float*)d_in[3];
    const float* w2 = (const float*)d_in[4];
    const float* b2 = (const float*)d_in[5];
    float* dout = (float*)d_out;

    const int N = N_NODES;
    const int E = N_EDGES;
    const int G = (N + SCB - 1) / SCB;  // 98 scan blocks

    // workspace layout
    f16*   h16A    = (f16*)d_ws;                   // N*64
    f16*   h16B    = h16A + (size_t)N * OUT_C;     // N*64
    f16*   h016    = h16B + (size_t)N * OUT_C;     // N*64
    int2*  csr_pack = (int2*)(h016 + (size_t)N * OUT_C);   // E int2
    float* dinv    = (float*)(csr_pack + E);       // N
    int*   cnt     = (int*)(dinv + N);             // N
    int*   row_ptr = cnt + N;                      // N+1
    int*   cursor  = row_ptr + (N + 1);            // N
    int*   perm    = cursor + N;                   // N
    f16*   w1h     = (f16*)(perm + N);             // 256*512
    f16*   w2h     = w1h + (size_t)HID_C * IN_C;   // 64*256
    int*   bsum    = (int*)(w2h + (size_t)OUT_C * HID_C);  // 128
    int*   boff    = bsum + 128;                           // 128
    int*   hist    = boff + 128;                           // 256
    int*   hcur    = hist + 256;                           // 256

    hipMemsetAsync(cnt, 0, (size_t)N * sizeof(int), stream);
    hipMemsetAsync(hist, 0, 256 * sizeof(int), stream);

    k_count<<<(E + 255) / 256, 256, 0, stream>>>(ei, cnt, E);
    k_dinv<<<(N + 255) / 256, 256, 0, stream>>>(cnt, dinv, N);
    k_scan1<<<G, 256, 0, stream>>>(cnt, bsum, N);
    k_scan2<<<1, 128, 0, stream>>>(bsum, boff, G, row_ptr, N, E);
    k_scan3<<<G, 256, 0, stream>>>(cnt, boff, row_ptr, cursor, N);
    k_fill<<<(E + 255) / 256, 256, 0, stream>>>(ei, dinv, cursor, csr_pack, E);

    // degree counting-sort
    k_hist<<<(N + 255) / 256, 256, 0, stream>>>(cnt, hist, N);
    k_hscan<<<1, 256, 0, stream>>>(hist, hcur);
    k_perm<<<(N + 255) / 256, 256, 0, stream>>>(cnt, hcur, perm, N);

    k_cast<<<(HID_C * IN_C + 255) / 256, 256, 0, stream>>>(w1, w1h, HID_C * IN_C);
    k_cast<<<(OUT_C * HID_C + 255) / 256, 256, 0, stream>>>(w2, w2h, OUT_C * HID_C);

    k_mlp2<<<(N + 63) / 64, 256, 0, stream>>>(x, w1h, b1, w2h, b2, h016, h16A, N);

    const int pwaves = (N + 7) / 8;                 // 12500 waves
    const int pblocks = (pwaves * 64 + 255) / 256;  // 3125 blocks
    for (int it = 0; it < K_ITERS; ++it) {
        const f16* pin = (it & 1) ? h16B : h16A;
        f16* pout = (it & 1) ? h16A : h16B;
        k_prop16<<<pblocks, 256, 0, stream>>>(pin, h016, pout, dout, row_ptr,
                                              csr_pack, dinv, perm, N,
                                              it == K_ITERS - 1 ? 1 : 0);
    }
}

// Round 11
// 629.087 us; speedup vs baseline: 1.9423x; 1.9423x over previous
//
#include <hip/hip_runtime.h>
#include <hip/hip_bf16.h>

#define N_NODES 100000
#define N_EDGES 1600000
#define IN_C 512
#define HID_C 256
#define OUT_C 64
#define K_ITERS 10
#define ALPHA 0.1f

typedef float f32x4 __attribute__((ext_vector_type(4)));
typedef _Float16 f16;
typedef _Float16 f16x4 __attribute__((ext_vector_type(4)));
typedef _Float16 f16x8 __attribute__((ext_vector_type(8)));

#define MFMA16(a, b, c) __builtin_amdgcn_mfma_f32_16x16x32_f16((a), (b), (c), 0, 0, 0)

__device__ __forceinline__ void gload16(const void* g, void* l) {
    __builtin_amdgcn_global_load_lds(
        (const __attribute__((address_space(1))) unsigned int*)g,
        (__attribute__((address_space(3))) unsigned int*)l, 16, 0, 0);
}

// ---------------------------------------------------------------------------
// CSR build kernels
// ---------------------------------------------------------------------------
__global__ void k_count(const int* __restrict__ ei, int* __restrict__ cnt, int E) {
    int e = blockIdx.x * blockDim.x + threadIdx.x;
    if (e < E) atomicAdd(&cnt[ei[E + e]], 1);
}

__global__ void k_dinv(const int* __restrict__ cnt, float* __restrict__ dinv, int n) {
    int i = blockIdx.x * blockDim.x + threadIdx.x;
    if (i < n) dinv[i] = rsqrtf((float)cnt[i] + 1.0f);  // +1 for self-loop
}

// ---------------------------------------------------------------------------
// Two-level scan: 1024 elems/block (256 thr x 4).
// ---------------------------------------------------------------------------
#define SCB 1024
__global__ __launch_bounds__(256) void k_scan1(const int* __restrict__ cnt,
                                               int* __restrict__ bsum, int n) {
    __shared__ int s[256];
    int b = blockIdx.x, t = threadIdx.x;
    int base = b * SCB + t * 4;
    int local = 0;
#pragma unroll
    for (int j = 0; j < 4; ++j) {
        int i = base + j;
        if (i < n) local += cnt[i];
    }
    s[t] = local;
    __syncthreads();
    for (int off = 1; off < 256; off <<= 1) {
        int u = (t >= off) ? s[t - off] : 0;
        __syncthreads();
        s[t] += u;
        __syncthreads();
    }
    if (t == 255) bsum[b] = s[255];
}

__global__ __launch_bounds__(128) void k_scan2(const int* __restrict__ bsum,
                                               int* __restrict__ boff, int G,
                                               int* __restrict__ row_ptr, int n, int total) {
    __shared__ int s[128];
    int t = threadIdx.x;
    int v = (t < G) ? bsum[t] : 0;
    s[t] = v;
    __syncthreads();
    for (int off = 1; off < 128; off <<= 1) {
        int u = (t >= off) ? s[t - off] : 0;
        __syncthreads();
        s[t] += u;
        __syncthreads();
    }
    if (t < G) boff[t] = s[t] - v;
    if (t == 0) row_ptr[n] = total;
}

__global__ __launch_bounds__(256) void k_scan3(const int* __restrict__ cnt,
                                               const int* __restrict__ boff,
                                               int* __restrict__ row_ptr,
                                               int* __restrict__ cursor, int n) {
    __shared__ int s[256];
    int b = blockIdx.x, t = threadIdx.x;
    int base = b * SCB + t * 4;
    int c4[4];
    int local = 0;
#pragma unroll
    for (int j = 0; j < 4; ++j) {
        int i = base + j;
        c4[j] = (i < n) ? cnt[i] : 0;
        local += c4[j];
    }
    s[t] = local;
    __syncthreads();
    for (int off = 1; off < 256; off <<= 1) {
        int u = (t >= off) ? s[t - off] : 0;
        __syncthreads();
        s[t] += u;
        __syncthreads();
    }
    int run = boff[b] + s[t] - local;
#pragma unroll
    for (int j = 0; j < 4; ++j) {
        int i = base + j;
        if (i < n) {
            row_ptr[i] = run;
            cursor[i] = run;
            run += c4[j];
        }
    }
}

// k_fill writes packed (src, weight) metadata: one 8B load per edge later.
__global__ void k_fill(const int* __restrict__ ei, const float* __restrict__ dinv,
                       int* __restrict__ cursor, int2* __restrict__ csr_pack, int E) {
    int e = blockIdx.x * blockDim.x + threadIdx.x;
    if (e < E) {
        int s = ei[e];
        int d = ei[E + e];
        int pos = atomicAdd(&cursor[d], 1);
        csr_pack[pos] = make_int2(s, __float_as_int(dinv[s] * dinv[d]));
    }
}

// ---------------------------------------------------------------------------
// Weight cast: f32 -> f16 (single precision term; rel err ~4.9e-4).
// ---------------------------------------------------------------------------
__global__ void k_cast(const float* __restrict__ in, f16* __restrict__ out, int n) {
    int i = blockIdx.x * blockDim.x + threadIdx.x;
    if (i < n) out[i] = (f16)in[i];
}

// ---------------------------------------------------------------------------
// Fused f16 MFMA MLP v5 (round-10 version, kept): x software-pipelined one
// k-step ahead so the vmcnt(0)+barrier drain finds the x loads landed.
// ---------------------------------------------------------------------------
__global__ __launch_bounds__(256, 4) void k_mlp2(
    const float* __restrict__ x,
    const f16* __restrict__ w1h,
    const float* __restrict__ b1,
    const f16* __restrict__ w2h,
    const float* __restrict__ b2,
    f16* __restrict__ h016, f16* __restrict__ hcur16, int n) {
    __shared__ __align__(16) union {
        struct {
            f16 Ah[64 * 40];   // 5 KB, rows padded to 40
            f16 Bh[256 * 32];  // 16 KB, chunk-swizzled
        } p1;
        struct {
            f16 Hh[64 * 264];  // 33.8 KB, rows padded to 264
        } p2;
    } sm;

    const int tid = threadIdx.x;
    const int l = tid & 63;
    const int w = tid >> 6;
    const int lr = l & 15;
    const int kg = l >> 4;
    const int row0 = blockIdx.x * 64;

    // A-staging coordinates (loop-invariant)
    const int r0 = tid >> 3, kk0 = (tid & 7) * 4;
    const int r1 = (tid + 256) >> 3, kk1 = (tid & 7) * 4;
    int gr0 = row0 + r0; if (gr0 >= n) gr0 = n - 1;
    int gr1 = row0 + r1; if (gr1 >= n) gr1 = n - 1;
    const float* xp0 = &x[(size_t)gr0 * IN_C + kk0];
    const float* xp1 = &x[(size_t)gr1 * IN_C + kk1];

    f32x4 acc[4][4];
#pragma unroll
    for (int m = 0; m < 4; ++m)
#pragma unroll
        for (int nf = 0; nf < 4; ++nf) acc[m][nf] = (f32x4)0.0f;

    // preload x for ks=0
    float4 xv0 = *(const float4*)xp0;
    float4 xv1 = *(const float4*)xp1;

    for (int ks = 0; ks < 16; ++ks) {
        const int k0 = ks * 32;
        // ---- stage B (w1 f16 tile, chunk-swizzled source) ----
#pragma unroll
        for (int i = 0; i < 4; ++i) {
            int slot = tid + 256 * i;
            int row = slot >> 2;
            int kc = (slot & 3) ^ ((row >> 1) & 3);
            size_t goff = (size_t)row * IN_C + k0 + kc * 8;
            int sbase = (w * 64 + 256 * i) * 8;
            gload16(w1h + goff, &sm.p1.Bh[sbase]);
        }
        // ---- stage A from prefetched regs (f32 -> f16) ----
        {
            f16x4 h4;
            h4.x = (f16)xv0.x; h4.y = (f16)xv0.y; h4.z = (f16)xv0.z; h4.w = (f16)xv0.w;
            *(f16x4*)&sm.p1.Ah[r0 * 40 + kk0] = h4;
            h4.x = (f16)xv1.x; h4.y = (f16)xv1.y; h4.z = (f16)xv1.z; h4.w = (f16)xv1.w;
            *(f16x4*)&sm.p1.Ah[r1 * 40 + kk1] = h4;
        }
        __syncthreads();

        // ---- prefetch next step's x during the MFMA phase ----
        if (ks < 15) {
            xv0 = *(const float4*)(xp0 + k0 + 32);
            xv1 = *(const float4*)(xp1 + k0 + 32);
        }

        f16x8 ah[4], bh[4];
#pragma unroll
        for (int m = 0; m < 4; ++m)
            ah[m] = *(const f16x8*)&sm.p1.Ah[(m * 16 + lr) * 40 + kg * 8];
#pragma unroll
        for (int nf = 0; nf < 4; ++nf) {
            int row = w * 64 + nf * 16 + lr;
            int kc = kg ^ ((row >> 1) & 3);
            bh[nf] = *(const f16x8*)&sm.p1.Bh[row * 32 + kc * 8];
        }
#pragma unroll
        for (int m = 0; m < 4; ++m)
#pragma unroll
            for (int nf = 0; nf < 4; ++nf)
                acc[m][nf] = MFMA16(ah[m], bh[nf], acc[m][nf]);
        __syncthreads();
    }

    // ---- epilogue 1: bias + relu -> f16 H1 in LDS ----
#pragma unroll
    for (int m = 0; m < 4; ++m)
#pragma unroll
        for (int nf = 0; nf < 4; ++nf) {
            int col = w * 64 + nf * 16 + lr;
            float bb = b1[col];
#pragma unroll
            for (int r = 0; r < 4; ++r) {
                int row = m * 16 + kg * 4 + r;
                float hv = acc[m][nf][r] + bb;
                hv = fmaxf(hv, 0.0f);
                sm.p2.Hh[row * 264 + col] = (f16)hv;
            }
        }
    __syncthreads();

    // ---- phase 2: out[64][64] = H1 @ W2^T + b2 ----
    f32x4 acc2[4];
#pragma unroll
    for (int m = 0; m < 4; ++m) acc2[m] = (f32x4)0.0f;
    const int col2 = w * 16 + lr;

#pragma unroll
    for (int k0 = 0; k0 < HID_C; k0 += 32) {
        f16x8 b2h = *(const f16x8*)&w2h[(size_t)col2 * HID_C + k0 + kg * 8];
#pragma unroll
        for (int m = 0; m < 4; ++m) {
            f16x8 a2h = *(const f16x8*)&sm.p2.Hh[(m * 16 + lr) * 264 + k0 + kg * 8];
            acc2[m] = MFMA16(a2h, b2h, acc2[m]);
        }
    }

    float bb2 = b2[col2];
#pragma unroll
    for (int m = 0; m < 4; ++m)
#pragma unroll
        for (int r = 0; r < 4; ++r) {
            int grow = row0 + m * 16 + kg * 4 + r;
            if (grow < n) {
                float vv = acc2[m][r] + bb2;
                size_t idx = (size_t)grow * OUT_C + col2;
                h016[idx] = (f16)vv;
                hcur16[idx] = (f16)vv;
            }
        }
}

// ---------------------------------------------------------------------------
// fp16 propagation v7: v5 structure (8 nodes/wave, 8 lanes x f16x8 per node;
// one gather instruction fetches EIGHT different 128B rows; natural node
// order -> all per-node metadata/self/h0/out accesses coalesced). NO perm
// (round-10 lesson: wave imbalance wastes instruction slots only; prop is
// bytes/latency-bound, and indirection scatters the coalesced accesses).
// New: next batch's metadata prefetched before consuming current batch.
// ---------------------------------------------------------------------------
__global__ __launch_bounds__(256) void k_prop16(const f16* __restrict__ hin,
                                                const f16* __restrict__ h016,
                                                f16* __restrict__ hout,
                                                float* __restrict__ dout,
                                                const int* __restrict__ row_ptr,
                                                const int2* __restrict__ csr_pack,
                                                const float* __restrict__ dinv,
                                                int n, int final_iter) {
    const int gwave = (blockIdx.x * blockDim.x + threadIdx.x) >> 6;
    const int lane = threadIdx.x & 63;
    const int g = lane >> 3;   // group 0..7 (node within wave)
    const int cl = lane & 7;   // channel octet: channels 8cl..8cl+7

    int node_raw = gwave * 8 + g;
    bool node_valid = node_raw < n;
    int node = node_valid ? node_raw : (n - 1);

    int e0 = row_ptr[node], e1 = row_ptr[node + 1];
    int nb = (e1 - e0 + 7) >> 3;
    // wave-max over the 8 groups (group id = lane bits 3..5)
    nb = max(nb, __shfl_xor(nb, 8));
    nb = max(nb, __shfl_xor(nb, 16));
    nb = max(nb, __shfl_xor(nb, 32));

    float a[8];
#pragma unroll
    for (int q = 0; q < 8; ++q) a[q] = 0.0f;
    const int gbase = g * 8;

    int2 meta = csr_pack[min(e0 + cl, N_EDGES - 1)];
    for (int b = 0; b < nb; ++b) {
        int mbase = e0 + b * 8;
        // prefetch next batch's metadata while this batch's gathers run
        int2 meta_next = meta;
        if (b + 1 < nb) meta_next = csr_pack[min(mbase + 8 + cl, N_EDGES - 1)];
#pragma unroll
        for (int j = 0; j < 8; ++j) {
            int s = __shfl(meta.x, gbase + j);
            float wv = __int_as_float(__shfl(meta.y, gbase + j));
            if (mbase + j < e1) {  // uniform within group
                f16x8 v = *(const f16x8*)&hin[(size_t)s * OUT_C + cl * 8];
#pragma unroll
                for (int q = 0; q < 8; ++q) a[q] += wv * (float)v[q];
            }
        }
        meta = meta_next;
    }

    float dv = dinv[node];
    float d2 = dv * dv;
    size_t idx = (size_t)node * OUT_C + cl * 8;
    f16x8 sv = *(const f16x8*)&hin[idx];
    f16x8 h0v = *(const f16x8*)&h016[idx];
    float r[8];
#pragma unroll
    for (int q = 0; q < 8; ++q)
        r[q] = (1.0f - ALPHA) * (a[q] + d2 * (float)sv[q]) + ALPHA * (float)h0v[q];

    if (node_valid) {
        f16x8 o;
#pragma unroll
        for (int q = 0; q < 8; ++q) o[q] = (f16)r[q];
        *(f16x8*)&hout[idx] = o;
        if (final_iter) {
            float4 o0 = make_float4(r[0], r[1], r[2], r[3]);
            float4 o1 = make_float4(r[4], r[5], r[6], r[7]);
            *(float4*)&dout[idx] = o0;
            *(float4*)&dout[idx + 4] = o1;
        }
    }
}

// ---------------------------------------------------------------------------
extern "C" void kernel_launch(void* const* d_in, const int* in_sizes, int n_in,
                              void* d_out, int out_size, void* d_ws, size_t ws_size,
                              hipStream_t stream) {
    const float* x  = (const float*)d_in[0];
    const int*   ei = (const int*)d_in[1];
    const float* w1 = (const float*)d_in[2];
    const float* b1 = (const float*)d_in[3];
    const float* w2 = (const float*)d_in[4];
    const float* b2 = (const float*)d_in[5];
    float* dout = (float*)d_out;

    const int N = N_NODES;
    const int E = N_EDGES;
    const int G = (N + SCB - 1) / SCB;  // 98 scan blocks

    // workspace layout
    f16*   h16A    = (f16*)d_ws;                   // N*64
    f16*   h16B    = h16A + (size_t)N * OUT_C;     // N*64
    f16*   h016    = h16B + (size_t)N * OUT_C;     // N*64
    int2*  csr_pack = (int2*)(h016 + (size_t)N * OUT_C);   // E int2
    float* dinv    = (float*)(csr_pack + E);       // N
    int*   cnt     = (int*)(dinv + N);             // N
    int*   row_ptr = cnt + N;                      // N+1
    int*   cursor  = row_ptr + (N + 1);            // N
    f16*   w1h     = (f16*)(cursor + N);           // 256*512
    f16*   w2h     = w1h + (size_t)HID_C * IN_C;   // 64*256
    int*   bsum    = (int*)(w2h + (size_t)OUT_C * HID_C);  // 128
    int*   boff    = bsum + 128;                           // 128

    hipMemsetAsync(cnt, 0, (size_t)N * sizeof(int), stream);

    k_count<<<(E + 255) / 256, 256, 0, stream>>>(ei, cnt, E);
    k_dinv<<<(N + 255) / 256, 256, 0, stream>>>(cnt, dinv, N);
    k_scan1<<<G, 256, 0, stream>>>(cnt, bsum, N);
    k_scan2<<<1, 128, 0, stream>>>(bsum, boff, G, row_ptr, N, E);
    k_scan3<<<G, 256, 0, stream>>>(cnt, boff, row_ptr, cursor, N);
    k_fill<<<(E + 255) / 256, 256, 0, stream>>>(ei, dinv, cursor, csr_pack, E);

    k_cast<<<(HID_C * IN_C + 255) / 256, 256, 0, stream>>>(w1, w1h, HID_C * IN_C);
    k_cast<<<(OUT_C * HID_C + 255) / 256, 256, 0, stream>>>(w2, w2h, OUT_C * HID_C);

    k_mlp2<<<(N + 63) / 64, 256, 0, stream>>>(x, w1h, b1, w2h, b2, h016, h16A, N);

    const int pwaves = (N + 7) / 8;                 // 12500 waves
    const int pblocks = (pwaves * 64 + 255) / 256;  // 3125 blocks
    for (int it = 0; it < K_ITERS; ++it) {
        const f16* pin = (it & 1) ? h16B : h16A;
        f16* pout = (it & 1) ? h16A : h16B;
        k_prop16<<<pblocks, 256, 0, stream>>>(pin, h016, pout, dout, row_ptr,
                                              csr_pack, dinv, N,
                                              it == K_ITERS - 1 ? 1 : 0);
    }
}

// Round 12
// 621.355 us; speedup vs baseline: 1.9665x; 1.0124x over previous
//
#include <hip/hip_runtime.h>
#include <hip/hip_bf16.h>

#define N_NODES 100000
#define N_EDGES 1600000
#define IN_C 512
#define HID_C 256
#define OUT_C 64
#define K_ITERS 10
#define ALPHA 0.1f

typedef float f32x4 __attribute__((ext_vector_type(4)));
typedef _Float16 f16;
typedef _Float16 f16x4 __attribute__((ext_vector_type(4)));
typedef _Float16 f16x8 __attribute__((ext_vector_type(8)));

#define MFMA16(a, b, c) __builtin_amdgcn_mfma_f32_16x16x32_f16((a), (b), (c), 0, 0, 0)

__device__ __forceinline__ void gload16(const void* g, void* l) {
    __builtin_amdgcn_global_load_lds(
        (const __attribute__((address_space(1))) unsigned int*)g,
        (__attribute__((address_space(3))) unsigned int*)l, 16, 0, 0);
}

// ---------------------------------------------------------------------------
// CSR build kernels
// ---------------------------------------------------------------------------
__global__ void k_count(const int* __restrict__ ei, int* __restrict__ cnt, int E) {
    int e = blockIdx.x * blockDim.x + threadIdx.x;
    if (e < E) atomicAdd(&cnt[ei[E + e]], 1);
}

__global__ void k_dinv(const int* __restrict__ cnt, float* __restrict__ dinv, int n) {
    int i = blockIdx.x * blockDim.x + threadIdx.x;
    if (i < n) dinv[i] = rsqrtf((float)cnt[i] + 1.0f);  // +1 for self-loop
}

// ---------------------------------------------------------------------------
// Two-level scan: 1024 elems/block (256 thr x 4).
// ---------------------------------------------------------------------------
#define SCB 1024
__global__ __launch_bounds__(256) void k_scan1(const int* __restrict__ cnt,
                                               int* __restrict__ bsum, int n) {
    __shared__ int s[256];
    int b = blockIdx.x, t = threadIdx.x;
    int base = b * SCB + t * 4;
    int local = 0;
#pragma unroll
    for (int j = 0; j < 4; ++j) {
        int i = base + j;
        if (i < n) local += cnt[i];
    }
    s[t] = local;
    __syncthreads();
    for (int off = 1; off < 256; off <<= 1) {
        int u = (t >= off) ? s[t - off] : 0;
        __syncthreads();
        s[t] += u;
        __syncthreads();
    }
    if (t == 255) bsum[b] = s[255];
}

__global__ __launch_bounds__(128) void k_scan2(const int* __restrict__ bsum,
                                               int* __restrict__ boff, int G,
                                               int* __restrict__ row_ptr, int n, int total) {
    __shared__ int s[128];
    int t = threadIdx.x;
    int v = (t < G) ? bsum[t] : 0;
    s[t] = v;
    __syncthreads();
    for (int off = 1; off < 128; off <<= 1) {
        int u = (t >= off) ? s[t - off] : 0;
        __syncthreads();
        s[t] += u;
        __syncthreads();
    }
    if (t < G) boff[t] = s[t] - v;
    if (t == 0) row_ptr[n] = total;
}

__global__ __launch_bounds__(256) void k_scan3(const int* __restrict__ cnt,
                                               const int* __restrict__ boff,
                                               int* __restrict__ row_ptr,
                                               int* __restrict__ cursor, int n) {
    __shared__ int s[256];
    int b = blockIdx.x, t = threadIdx.x;
    int base = b * SCB + t * 4;
    int c4[4];
    int local = 0;
#pragma unroll
    for (int j = 0; j < 4; ++j) {
        int i = base + j;
        c4[j] = (i < n) ? cnt[i] : 0;
        local += c4[j];
    }
    s[t] = local;
    __syncthreads();
    for (int off = 1; off < 256; off <<= 1) {
        int u = (t >= off) ? s[t - off] : 0;
        __syncthreads();
        s[t] += u;
        __syncthreads();
    }
    int run = boff[b] + s[t] - local;
#pragma unroll
    for (int j = 0; j < 4; ++j) {
        int i = base + j;
        if (i < n) {
            row_ptr[i] = run;
            cursor[i] = run;
            run += c4[j];
        }
    }
}

// k_fill writes packed (src, weight) metadata: one 8B load per edge later.
__global__ void k_fill(const int* __restrict__ ei, const float* __restrict__ dinv,
                       int* __restrict__ cursor, int2* __restrict__ csr_pack, int E) {
    int e = blockIdx.x * blockDim.x + threadIdx.x;
    if (e < E) {
        int s = ei[e];
        int d = ei[E + e];
        int pos = atomicAdd(&cursor[d], 1);
        csr_pack[pos] = make_int2(s, __float_as_int(dinv[s] * dinv[d]));
    }
}

// ---------------------------------------------------------------------------
// Weight cast: f32 -> f16 (single precision term; rel err ~4.9e-4).
// ---------------------------------------------------------------------------
__global__ void k_cast(const float* __restrict__ in, f16* __restrict__ out, int n) {
    int i = blockIdx.x * blockDim.x + threadIdx.x;
    if (i < n) out[i] = (f16)in[i];
}

// ---------------------------------------------------------------------------
// Fused f16 MFMA MLP v6: double-buffered single-barrier K-loop (T3 2-phase).
// Per step: (1) issue x loads for ks+1, (2) issue B gload16 for ks+1 into
// buf^1, (3) ds_read + 16 MFMA from buf, (4) cvt+ds_write A(ks+1) into buf^1,
// (5) ONE barrier. The vmcnt(0) drain at the barrier finds stage(ks+1) loads
// ~an MFMA-phase old -> latency hidden. Barriers 32 -> 17 per block.
// LDS = 2*(5+16) = 42 KB -> 3 blocks/CU.
// ---------------------------------------------------------------------------
__global__ __launch_bounds__(256, 3) void k_mlp2(
    const float* __restrict__ x,
    const f16* __restrict__ w1h,
    const float* __restrict__ b1,
    const f16* __restrict__ w2h,
    const float* __restrict__ b2,
    f16* __restrict__ h016, f16* __restrict__ hcur16, int n) {
    __shared__ __align__(16) union {
        struct {
            f16 Ah[2][64 * 40];   // 2 x 5 KB
            f16 Bh[2][256 * 32];  // 2 x 16 KB, chunk-swizzled
        } p1;
        struct {
            f16 Hh[64 * 264];     // 33.8 KB
        } p2;
    } sm;

    const int tid = threadIdx.x;
    const int l = tid & 63;
    const int w = tid >> 6;
    const int lr = l & 15;
    const int kg = l >> 4;
    const int row0 = blockIdx.x * 64;

    // A-staging coordinates (loop-invariant)
    const int r0 = tid >> 3, kk0 = (tid & 7) * 4;
    const int r1 = (tid + 256) >> 3;
    int gr0 = row0 + r0; if (gr0 >= n) gr0 = n - 1;
    int gr1 = row0 + r1; if (gr1 >= n) gr1 = n - 1;
    const float* xp0 = &x[(size_t)gr0 * IN_C + kk0];
    const float* xp1 = &x[(size_t)gr1 * IN_C + kk0];

    // B-staging coordinates (loop-invariant): 4 slots per thread
    int brow[4], bkc[4], bsb[4];
#pragma unroll
    for (int i = 0; i < 4; ++i) {
        int slot = tid + 256 * i;
        brow[i] = slot >> 2;
        bkc[i] = (slot & 3) ^ ((brow[i] >> 1) & 3);
        bsb[i] = (w * 64 + 256 * i) * 8;
    }

    f32x4 acc[4][4];
#pragma unroll
    for (int m = 0; m < 4; ++m)
#pragma unroll
        for (int nf = 0; nf < 4; ++nf) acc[m][nf] = (f32x4)0.0f;

    // ---- prologue: stage ks=0 into buf 0 ----
    {
        float4 v0 = *(const float4*)xp0;
        float4 v1 = *(const float4*)xp1;
#pragma unroll
        for (int i = 0; i < 4; ++i)
            gload16(w1h + (size_t)brow[i] * IN_C + bkc[i] * 8, &sm.p1.Bh[0][bsb[i]]);
        f16x4 h4;
        h4.x = (f16)v0.x; h4.y = (f16)v0.y; h4.z = (f16)v0.z; h4.w = (f16)v0.w;
        *(f16x4*)&sm.p1.Ah[0][r0 * 40 + kk0] = h4;
        h4.x = (f16)v1.x; h4.y = (f16)v1.y; h4.z = (f16)v1.z; h4.w = (f16)v1.w;
        *(f16x4*)&sm.p1.Ah[0][r1 * 40 + kk0] = h4;
    }
    __syncthreads();

    for (int ks = 0; ks < 16; ++ks) {
        const int cur = ks & 1;
        float4 xv0, xv1;
        if (ks < 15) {
            const int kn = (ks + 1) * 32;
            // issue x loads FIRST (so waiting for them later = vmcnt(4), not 0)
            xv0 = *(const float4*)(xp0 + kn);
            xv1 = *(const float4*)(xp1 + kn);
            // then async B staging for ks+1 into the other buffer
#pragma unroll
            for (int i = 0; i < 4; ++i)
                gload16(w1h + (size_t)brow[i] * IN_C + kn + bkc[i] * 8,
                        &sm.p1.Bh[cur ^ 1][bsb[i]]);
        }

        // ---- compute from buf[cur] ----
        f16x8 ah[4], bh[4];
#pragma unroll
        for (int m = 0; m < 4; ++m)
            ah[m] = *(const f16x8*)&sm.p1.Ah[cur][(m * 16 + lr) * 40 + kg * 8];
#pragma unroll
        for (int nf = 0; nf < 4; ++nf) {
            int row = w * 64 + nf * 16 + lr;
            int kc = kg ^ ((row >> 1) & 3);
            bh[nf] = *(const f16x8*)&sm.p1.Bh[cur][row * 32 + kc * 8];
        }
#pragma unroll
        for (int m = 0; m < 4; ++m)
#pragma unroll
            for (int nf = 0; nf < 4; ++nf)
                acc[m][nf] = MFMA16(ah[m], bh[nf], acc[m][nf]);

        // ---- write A(ks+1) after the MFMA phase (x loads now landed) ----
        if (ks < 15) {
            f16x4 h4;
            h4.x = (f16)xv0.x; h4.y = (f16)xv0.y; h4.z = (f16)xv0.z; h4.w = (f16)xv0.w;
            *(f16x4*)&sm.p1.Ah[cur ^ 1][r0 * 40 + kk0] = h4;
            h4.x = (f16)xv1.x; h4.y = (f16)xv1.y; h4.z = (f16)xv1.z; h4.w = (f16)xv1.w;
            *(f16x4*)&sm.p1.Ah[cur ^ 1][r1 * 40 + kk0] = h4;
        }
        __syncthreads();  // single barrier per step
    }

    // ---- epilogue 1: bias + relu -> f16 H1 in LDS ----
#pragma unroll
    for (int m = 0; m < 4; ++m)
#pragma unroll
        for (int nf = 0; nf < 4; ++nf) {
            int col = w * 64 + nf * 16 + lr;
            float bb = b1[col];
#pragma unroll
            for (int r = 0; r < 4; ++r) {
                int row = m * 16 + kg * 4 + r;
                float hv = acc[m][nf][r] + bb;
                hv = fmaxf(hv, 0.0f);
                sm.p2.Hh[row * 264 + col] = (f16)hv;
            }
        }
    __syncthreads();

    // ---- phase 2: out[64][64] = H1 @ W2^T + b2 ----
    f32x4 acc2[4];
#pragma unroll
    for (int m = 0; m < 4; ++m) acc2[m] = (f32x4)0.0f;
    const int col2 = w * 16 + lr;

#pragma unroll
    for (int k0 = 0; k0 < HID_C; k0 += 32) {
        f16x8 b2h = *(const f16x8*)&w2h[(size_t)col2 * HID_C + k0 + kg * 8];
#pragma unroll
        for (int m = 0; m < 4; ++m) {
            f16x8 a2h = *(const f16x8*)&sm.p2.Hh[(m * 16 + lr) * 264 + k0 + kg * 8];
            acc2[m] = MFMA16(a2h, b2h, acc2[m]);
        }
    }

    float bb2 = b2[col2];
#pragma unroll
    for (int m = 0; m < 4; ++m)
#pragma unroll
        for (int r = 0; r < 4; ++r) {
            int grow = row0 + m * 16 + kg * 4 + r;
            if (grow < n) {
                float vv = acc2[m][r] + bb2;
                size_t idx = (size_t)grow * OUT_C + col2;
                h016[idx] = (f16)vv;
                hcur16[idx] = (f16)vv;
            }
        }
}

// ---------------------------------------------------------------------------
// fp16 propagation v7 (unchanged from round 11): 8 nodes/wave, 8 lanes x
// f16x8 per node; one gather instruction fetches EIGHT different 128B rows;
// natural node order keeps metadata/self/h0/out accesses coalesced; next
// batch's metadata prefetched. Near the random-gather bytes floor
// (~205 MB/iter at ~4.6 TB/s effective).
// ---------------------------------------------------------------------------
__global__ __launch_bounds__(256) void k_prop16(const f16* __restrict__ hin,
                                                const f16* __restrict__ h016,
                                                f16* __restrict__ hout,
                                                float* __restrict__ dout,
                                                const int* __restrict__ row_ptr,
                                                const int2* __restrict__ csr_pack,
                                                const float* __restrict__ dinv,
                                                int n, int final_iter) {
    const int gwave = (blockIdx.x * blockDim.x + threadIdx.x) >> 6;
    const int lane = threadIdx.x & 63;
    const int g = lane >> 3;   // group 0..7 (node within wave)
    const int cl = lane & 7;   // channel octet: channels 8cl..8cl+7

    int node_raw = gwave * 8 + g;
    bool node_valid = node_raw < n;
    int node = node_valid ? node_raw : (n - 1);

    int e0 = row_ptr[node], e1 = row_ptr[node + 1];
    int nb = (e1 - e0 + 7) >> 3;
    nb = max(nb, __shfl_xor(nb, 8));
    nb = max(nb, __shfl_xor(nb, 16));
    nb = max(nb, __shfl_xor(nb, 32));

    float a[8];
#pragma unroll
    for (int q = 0; q < 8; ++q) a[q] = 0.0f;
    const int gbase = g * 8;

    int2 meta = csr_pack[min(e0 + cl, N_EDGES - 1)];
    for (int b = 0; b < nb; ++b) {
        int mbase = e0 + b * 8;
        int2 meta_next = meta;
        if (b + 1 < nb) meta_next = csr_pack[min(mbase + 8 + cl, N_EDGES - 1)];
#pragma unroll
        for (int j = 0; j < 8; ++j) {
            int s = __shfl(meta.x, gbase + j);
            float wv = __int_as_float(__shfl(meta.y, gbase + j));
            if (mbase + j < e1) {  // uniform within group
                f16x8 v = *(const f16x8*)&hin[(size_t)s * OUT_C + cl * 8];
#pragma unroll
                for (int q = 0; q < 8; ++q) a[q] += wv * (float)v[q];
            }
        }
        meta = meta_next;
    }

    float dv = dinv[node];
    float d2 = dv * dv;
    size_t idx = (size_t)node * OUT_C + cl * 8;
    f16x8 sv = *(const f16x8*)&hin[idx];
    f16x8 h0v = *(const f16x8*)&h016[idx];
    float r[8];
#pragma unroll
    for (int q = 0; q < 8; ++q)
        r[q] = (1.0f - ALPHA) * (a[q] + d2 * (float)sv[q]) + ALPHA * (float)h0v[q];

    if (node_valid) {
        f16x8 o;
#pragma unroll
        for (int q = 0; q < 8; ++q) o[q] = (f16)r[q];
        *(f16x8*)&hout[idx] = o;
        if (final_iter) {
            float4 o0 = make_float4(r[0], r[1], r[2], r[3]);
            float4 o1 = make_float4(r[4], r[5], r[6], r[7]);
            *(float4*)&dout[idx] = o0;
            *(float4*)&dout[idx + 4] = o1;
        }
    }
}

// ---------------------------------------------------------------------------
extern "C" void kernel_launch(void* const* d_in, const int* in_sizes, int n_in,
                              void* d_out, int out_size, void* d_ws, size_t ws_size,
                              hipStream_t stream) {
    const float* x  = (const float*)d_in[0];
    const int*   ei = (const int*)d_in[1];
    const float* w1 = (const float*)d_in[2];
    const float* b1 = (const float*)d_in[3];
    const float* w2 = (const float*)d_in[4];
    const float* b2 = (const float*)d_in[5];
    float* dout = (float*)d_out;

    const int N = N_NODES;
    const int E = N_EDGES;
    const int G = (N + SCB - 1) / SCB;  // 98 scan blocks

    // workspace layout
    f16*   h16A    = (f16*)d_ws;                   // N*64
    f16*   h16B    = h16A + (size_t)N * OUT_C;     // N*64
    f16*   h016    = h16B + (size_t)N * OUT_C;     // N*64
    int2*  csr_pack = (int2*)(h016 + (size_t)N * OUT_C);   // E int2
    float* dinv    = (float*)(csr_pack + E);       // N
    int*   cnt     = (int*)(dinv + N);             // N
    int*   row_ptr = cnt + N;                      // N+1
    int*   cursor  = row_ptr + (N + 1);            // N
    f16*   w1h     = (f16*)(cursor + N);           // 256*512
    f16*   w2h     = w1h + (size_t)HID_C * IN_C;   // 64*256
    int*   bsum    = (int*)(w2h + (size_t)OUT_C * HID_C);  // 128
    int*   boff    = bsum + 128;                           // 128

    hipMemsetAsync(cnt, 0, (size_t)N * sizeof(int), stream);

    k_count<<<(E + 255) / 256, 256, 0, stream>>>(ei, cnt, E);
    k_dinv<<<(N + 255) / 256, 256, 0, stream>>>(cnt, dinv, N);
    k_scan1<<<G, 256, 0, stream>>>(cnt, bsum, N);
    k_scan2<<<1, 128, 0, stream>>>(bsum, boff, G, row_ptr, N, E);
    k_scan3<<<G, 256, 0, stream>>>(cnt, boff, row_ptr, cursor, N);
    k_fill<<<(E + 255) / 256, 256, 0, stream>>>(ei, dinv, cursor, csr_pack, E);

    k_cast<<<(HID_C * IN_C + 255) / 256, 256, 0, stream>>>(w1, w1h, HID_C * IN_C);
    k_cast<<<(OUT_C * HID_C + 255) / 256, 256, 0, stream>>>(w2, w2h, OUT_C * HID_C);

    k_mlp2<<<(N + 63) / 64, 256, 0, stream>>>(x, w1h, b1, w2h, b2, h016, h16A, N);

    const int pwaves = (N + 7) / 8;                 // 12500 waves
    const int pblocks = (pwaves * 64 + 255) / 256;  // 3125 blocks
    for (int it = 0; it < K_ITERS; ++it) {
        const f16* pin = (it & 1) ? h16B : h16A;
        f16* pout = (it & 1) ? h16A : h16B;
        k_prop16<<<pblocks, 256, 0, stream>>>(pin, h016, pout, dout, row_ptr,
                                              csr_pack, dinv, N,
                                              it == K_ITERS - 1 ? 1 : 0);
    }
}

// Round 13
// 603.464 us; speedup vs baseline: 2.0248x; 1.0296x over previous
//
#include <hip/hip_runtime.h>
#include <hip/hip_bf16.h>

#define N_NODES 100000
#define N_EDGES 1600000
#define IN_C 512
#define HID_C 256
#define OUT_C 64
#define K_ITERS 10
#define ALPHA 0.1f

typedef float f32x4 __attribute__((ext_vector_type(4)));
typedef _Float16 f16;
typedef _Float16 f16x4 __attribute__((ext_vector_type(4)));
typedef _Float16 f16x8 __attribute__((ext_vector_type(8)));

#define MFMA16(a, b, c) __builtin_amdgcn_mfma_f32_16x16x32_f16((a), (b), (c), 0, 0, 0)

__device__ __forceinline__ void gload16(const void* g, void* l) {
    __builtin_amdgcn_global_load_lds(
        (const __attribute__((address_space(1))) unsigned int*)g,
        (__attribute__((address_space(3))) unsigned int*)l, 16, 0, 0);
}

// ---------------------------------------------------------------------------
// CSR build kernels
// ---------------------------------------------------------------------------
__global__ void k_count(const int* __restrict__ ei, int* __restrict__ cnt, int E) {
    int e = blockIdx.x * blockDim.x + threadIdx.x;
    if (e < E) atomicAdd(&cnt[ei[E + e]], 1);
}

__global__ void k_dinv(const int* __restrict__ cnt, float* __restrict__ dinv, int n) {
    int i = blockIdx.x * blockDim.x + threadIdx.x;
    if (i < n) dinv[i] = rsqrtf((float)cnt[i] + 1.0f);  // +1 for self-loop
}

// ---------------------------------------------------------------------------
// Two-level scan: 1024 elems/block (256 thr x 4).
// ---------------------------------------------------------------------------
#define SCB 1024
__global__ __launch_bounds__(256) void k_scan1(const int* __restrict__ cnt,
                                               int* __restrict__ bsum, int n) {
    __shared__ int s[256];
    int b = blockIdx.x, t = threadIdx.x;
    int base = b * SCB + t * 4;
    int local = 0;
#pragma unroll
    for (int j = 0; j < 4; ++j) {
        int i = base + j;
        if (i < n) local += cnt[i];
    }
    s[t] = local;
    __syncthreads();
    for (int off = 1; off < 256; off <<= 1) {
        int u = (t >= off) ? s[t - off] : 0;
        __syncthreads();
        s[t] += u;
        __syncthreads();
    }
    if (t == 255) bsum[b] = s[255];
}

__global__ __launch_bounds__(128) void k_scan2(const int* __restrict__ bsum,
                                               int* __restrict__ boff, int G,
                                               int* __restrict__ row_ptr, int n, int total) {
    __shared__ int s[128];
    int t = threadIdx.x;
    int v = (t < G) ? bsum[t] : 0;
    s[t] = v;
    __syncthreads();
    for (int off = 1; off < 128; off <<= 1) {
        int u = (t >= off) ? s[t - off] : 0;
        __syncthreads();
        s[t] += u;
        __syncthreads();
    }
    if (t < G) boff[t] = s[t] - v;
    if (t == 0) row_ptr[n] = total;
}

__global__ __launch_bounds__(256) void k_scan3(const int* __restrict__ cnt,
                                               const int* __restrict__ boff,
                                               int* __restrict__ row_ptr,
                                               int* __restrict__ cursor, int n) {
    __shared__ int s[256];
    int b = blockIdx.x, t = threadIdx.x;
    int base = b * SCB + t * 4;
    int c4[4];
    int local = 0;
#pragma unroll
    for (int j = 0; j < 4; ++j) {
        int i = base + j;
        c4[j] = (i < n) ? cnt[i] : 0;
        local += c4[j];
    }
    s[t] = local;
    __syncthreads();
    for (int off = 1; off < 256; off <<= 1) {
        int u = (t >= off) ? s[t - off] : 0;
        __syncthreads();
        s[t] += u;
        __syncthreads();
    }
    int run = boff[b] + s[t] - local;
#pragma unroll
    for (int j = 0; j < 4; ++j) {
        int i = base + j;
        if (i < n) {
            row_ptr[i] = run;
            cursor[i] = run;
            run += c4[j];
        }
    }
}

// k_fill writes packed (src, weight) metadata: one 8B load per edge later.
__global__ void k_fill(const int* __restrict__ ei, const float* __restrict__ dinv,
                       int* __restrict__ cursor, int2* __restrict__ csr_pack, int E) {
    int e = blockIdx.x * blockDim.x + threadIdx.x;
    if (e < E) {
        int s = ei[e];
        int d = ei[E + e];
        int pos = atomicAdd(&cursor[d], 1);
        csr_pack[pos] = make_int2(s, __float_as_int(dinv[s] * dinv[d]));
    }
}

// ---------------------------------------------------------------------------
// Weight cast: f32 -> f16 (single precision term; rel err ~4.9e-4).
// ---------------------------------------------------------------------------
__global__ void k_cast(const float* __restrict__ in, f16* __restrict__ out, int n) {
    int i = blockIdx.x * blockDim.x + threadIdx.x;
    if (i < n) out[i] = (f16)in[i];
}

// ---------------------------------------------------------------------------
// Fused f16 MFMA MLP v7: M-tile 128 (512 thr, 8 waves, wave grid 2x4 over
// the 128x256 H1 tile) + round-12's double-buffered single-barrier K-loop.
// Halves the dominant cost: per-block w1 re-staging (400 -> 200 MB total);
// doubles MFMA per staged byte. LDS: dbuf 52 KB / phase-2 Hh 66 KB -> union
// 66 KB -> 2 blocks/CU (16 waves/CU, 4/SIMD).
// ---------------------------------------------------------------------------
__global__ __launch_bounds__(512, 4) void k_mlp2(
    const float* __restrict__ x,
    const f16* __restrict__ w1h,
    const float* __restrict__ b1,
    const f16* __restrict__ w2h,
    const float* __restrict__ b2,
    f16* __restrict__ h016, f16* __restrict__ hcur16, int n) {
    __shared__ __align__(16) union {
        struct {
            f16 Ah[2][128 * 40];  // 2 x 10 KB, rows padded to 40
            f16 Bh[2][256 * 32];  // 2 x 16 KB, chunk-swizzled
        } p1;
        struct {
            f16 Hh[128 * 264];    // 66 KB, rows padded to 264
        } p2;
    } sm;

    const int tid = threadIdx.x;
    const int l = tid & 63;
    const int w = tid >> 6;      // wave 0..7
    const int wr = w >> 2;       // wave row 0..1 (64 rows each)
    const int wc = w & 3;        // wave col 0..3 (64 cols each)
    const int lr = l & 15;
    const int kg = l >> 4;
    const int row0 = blockIdx.x * 128;

    // A-staging coordinates: 128x32 floats = 1024 float4, 2 per thread
    const int r0 = tid >> 3, kk0 = (tid & 7) * 4;  // rows 0..63, 64..127
    int gr0 = row0 + r0;       if (gr0 >= n) gr0 = n - 1;
    int gr1 = row0 + r0 + 64;  if (gr1 >= n) gr1 = n - 1;
    const float* xp0 = &x[(size_t)gr0 * IN_C + kk0];
    const float* xp1 = &x[(size_t)gr1 * IN_C + kk0];

    // B-staging coordinates: 1024 16B chunks, 2 per thread
    int brow[2], bkc[2], bsb[2];
#pragma unroll
    for (int i = 0; i < 2; ++i) {
        int slot = tid + 512 * i;
        brow[i] = slot >> 2;
        bkc[i] = (slot & 3) ^ ((brow[i] >> 1) & 3);
        bsb[i] = (w * 64 + 512 * i) * 8;
    }

    f32x4 acc[4][4];
#pragma unroll
    for (int m = 0; m < 4; ++m)
#pragma unroll
        for (int nf = 0; nf < 4; ++nf) acc[m][nf] = (f32x4)0.0f;

    // ---- prologue: stage ks=0 into buf 0 ----
    {
        float4 v0 = *(const float4*)xp0;
        float4 v1 = *(const float4*)xp1;
#pragma unroll
        for (int i = 0; i < 2; ++i)
            gload16(w1h + (size_t)brow[i] * IN_C + bkc[i] * 8, &sm.p1.Bh[0][bsb[i]]);
        f16x4 h4;
        h4.x = (f16)v0.x; h4.y = (f16)v0.y; h4.z = (f16)v0.z; h4.w = (f16)v0.w;
        *(f16x4*)&sm.p1.Ah[0][r0 * 40 + kk0] = h4;
        h4.x = (f16)v1.x; h4.y = (f16)v1.y; h4.z = (f16)v1.z; h4.w = (f16)v1.w;
        *(f16x4*)&sm.p1.Ah[0][(r0 + 64) * 40 + kk0] = h4;
    }
    __syncthreads();

    for (int ks = 0; ks < 16; ++ks) {
        const int cur = ks & 1;
        float4 xv0, xv1;
        if (ks < 15) {
            const int kn = (ks + 1) * 32;
            // issue x loads FIRST (waiting for them later = counted vmcnt)
            xv0 = *(const float4*)(xp0 + kn);
            xv1 = *(const float4*)(xp1 + kn);
            // then async B staging for ks+1 into the other buffer
#pragma unroll
            for (int i = 0; i < 2; ++i)
                gload16(w1h + (size_t)brow[i] * IN_C + kn + bkc[i] * 8,
                        &sm.p1.Bh[cur ^ 1][bsb[i]]);
        }

        // ---- compute from buf[cur] ----
        f16x8 ah[4], bh[4];
#pragma unroll
        for (int m = 0; m < 4; ++m)
            ah[m] = *(const f16x8*)&sm.p1.Ah[cur][(wr * 64 + m * 16 + lr) * 40 + kg * 8];
#pragma unroll
        for (int nf = 0; nf < 4; ++nf) {
            int row = wc * 64 + nf * 16 + lr;
            int kc = kg ^ ((row >> 1) & 3);
            bh[nf] = *(const f16x8*)&sm.p1.Bh[cur][row * 32 + kc * 8];
        }
#pragma unroll
        for (int m = 0; m < 4; ++m)
#pragma unroll
            for (int nf = 0; nf < 4; ++nf)
                acc[m][nf] = MFMA16(ah[m], bh[nf], acc[m][nf]);

        // ---- write A(ks+1) after the MFMA phase (x loads now landed) ----
        if (ks < 15) {
            f16x4 h4;
            h4.x = (f16)xv0.x; h4.y = (f16)xv0.y; h4.z = (f16)xv0.z; h4.w = (f16)xv0.w;
            *(f16x4*)&sm.p1.Ah[cur ^ 1][r0 * 40 + kk0] = h4;
            h4.x = (f16)xv1.x; h4.y = (f16)xv1.y; h4.z = (f16)xv1.z; h4.w = (f16)xv1.w;
            *(f16x4*)&sm.p1.Ah[cur ^ 1][(r0 + 64) * 40 + kk0] = h4;
        }
        __syncthreads();  // single barrier per step
    }

    // ---- epilogue 1: bias + relu -> f16 H1 in LDS ----
#pragma unroll
    for (int m = 0; m < 4; ++m)
#pragma unroll
        for (int nf = 0; nf < 4; ++nf) {
            int col = wc * 64 + nf * 16 + lr;
            float bb = b1[col];
#pragma unroll
            for (int r = 0; r < 4; ++r) {
                int row = wr * 64 + m * 16 + kg * 4 + r;
                float hv = acc[m][nf][r] + bb;
                hv = fmaxf(hv, 0.0f);
                sm.p2.Hh[row * 264 + col] = (f16)hv;
            }
        }
    __syncthreads();

    // ---- phase 2: out[128][64] = H1 @ W2^T + b2 ----
    // waves w<4 handle row-frags 0..3 (rows 0..63), w>=4 rows 64..127;
    // col2 = (w&3)*16+lr -> each wave reads only 16 w2 rows (8 KB).
    f32x4 acc2[4];
#pragma unroll
    for (int m = 0; m < 4; ++m) acc2[m] = (f32x4)0.0f;
    const int col2 = wc * 16 + lr;
    const int rbase = wr * 64;

#pragma unroll
    for (int k0 = 0; k0 < HID_C; k0 += 32) {
        f16x8 b2h = *(const f16x8*)&w2h[(size_t)col2 * HID_C + k0 + kg * 8];
#pragma unroll
        for (int m = 0; m < 4; ++m) {
            f16x8 a2h = *(const f16x8*)&sm.p2.Hh[(rbase + m * 16 + lr) * 264 + k0 + kg * 8];
            acc2[m] = MFMA16(a2h, b2h, acc2[m]);
        }
    }

    float bb2 = b2[col2];
#pragma unroll
    for (int m = 0; m < 4; ++m)
#pragma unroll
        for (int r = 0; r < 4; ++r) {
            int grow = row0 + rbase + m * 16 + kg * 4 + r;
            if (grow < n) {
                float vv = acc2[m][r] + bb2;
                size_t idx = (size_t)grow * OUT_C + col2;
                h016[idx] = (f16)vv;
                hcur16[idx] = (f16)vv;
            }
        }
}

// ---------------------------------------------------------------------------
// fp16 propagation v7 (unchanged): 8 nodes/wave, 8 lanes x f16x8 per node;
// one gather instruction fetches EIGHT different 128B rows; natural node
// order keeps metadata/self/h0/out accesses coalesced; next batch's metadata
// prefetched. ~205 MB/iter of random 64B-line gathers at ~4.6 TB/s effective.
// ---------------------------------------------------------------------------
__global__ __launch_bounds__(256) void k_prop16(const f16* __restrict__ hin,
                                                const f16* __restrict__ h016,
                                                f16* __restrict__ hout,
                                                float* __restrict__ dout,
                                                const int* __restrict__ row_ptr,
                                                const int2* __restrict__ csr_pack,
                                                const float* __restrict__ dinv,
                                                int n, int final_iter) {
    const int gwave = (blockIdx.x * blockDim.x + threadIdx.x) >> 6;
    const int lane = threadIdx.x & 63;
    const int g = lane >> 3;   // group 0..7 (node within wave)
    const int cl = lane & 7;   // channel octet: channels 8cl..8cl+7

    int node_raw = gwave * 8 + g;
    bool node_valid = node_raw < n;
    int node = node_valid ? node_raw : (n - 1);

    int e0 = row_ptr[node], e1 = row_ptr[node + 1];
    int nb = (e1 - e0 + 7) >> 3;
    nb = max(nb, __shfl_xor(nb, 8));
    nb = max(nb, __shfl_xor(nb, 16));
    nb = max(nb, __shfl_xor(nb, 32));

    float a[8];
#pragma unroll
    for (int q = 0; q < 8; ++q) a[q] = 0.0f;
    const int gbase = g * 8;

    int2 meta = csr_pack[min(e0 + cl, N_EDGES - 1)];
    for (int b = 0; b < nb; ++b) {
        int mbase = e0 + b * 8;
        int2 meta_next = meta;
        if (b + 1 < nb) meta_next = csr_pack[min(mbase + 8 + cl, N_EDGES - 1)];
#pragma unroll
        for (int j = 0; j < 8; ++j) {
            int s = __shfl(meta.x, gbase + j);
            float wv = __int_as_float(__shfl(meta.y, gbase + j));
            if (mbase + j < e1) {  // uniform within group
                f16x8 v = *(const f16x8*)&hin[(size_t)s * OUT_C + cl * 8];
#pragma unroll
                for (int q = 0; q < 8; ++q) a[q] += wv * (float)v[q];
            }
        }
        meta = meta_next;
    }

    float dv = dinv[node];
    float d2 = dv * dv;
    size_t idx = (size_t)node * OUT_C + cl * 8;
    f16x8 sv = *(const f16x8*)&hin[idx];
    f16x8 h0v = *(const f16x8*)&h016[idx];
    float r[8];
#pragma unroll
    for (int q = 0; q < 8; ++q)
        r[q] = (1.0f - ALPHA) * (a[q] + d2 * (float)sv[q]) + ALPHA * (float)h0v[q];

    if (node_valid) {
        f16x8 o;
#pragma unroll
        for (int q = 0; q < 8; ++q) o[q] = (f16)r[q];
        *(f16x8*)&hout[idx] = o;
        if (final_iter) {
            float4 o0 = make_float4(r[0], r[1], r[2], r[3]);
            float4 o1 = make_float4(r[4], r[5], r[6], r[7]);
            *(float4*)&dout[idx] = o0;
            *(float4*)&dout[idx + 4] = o1;
        }
    }
}

// ---------------------------------------------------------------------------
extern "C" void kernel_launch(void* const* d_in, const int* in_sizes, int n_in,
                              void* d_out, int out_size, void* d_ws, size_t ws_size,
                              hipStream_t stream) {
    const float* x  = (const float*)d_in[0];
    const int*   ei = (const int*)d_in[1];
    const float* w1 = (const float*)d_in[2];
    const float* b1 = (const float*)d_in[3];
    const float* w2 = (const float*)d_in[4];
    const float* b2 = (const float*)d_in[5];
    float* dout = (float*)d_out;

    const int N = N_NODES;
    const int E = N_EDGES;
    const int G = (N + SCB - 1) / SCB;  // 98 scan blocks

    // workspace layout
    f16*   h16A    = (f16*)d_ws;                   // N*64
    f16*   h16B    = h16A + (size_t)N * OUT_C;     // N*64
    f16*   h016    = h16B + (size_t)N * OUT_C;     // N*64
    int2*  csr_pack = (int2*)(h016 + (size_t)N * OUT_C);   // E int2
    float* dinv    = (float*)(csr_pack + E);       // N
    int*   cnt     = (int*)(dinv + N);             // N
    int*   row_ptr = cnt + N;                      // N+1
    int*   cursor  = row_ptr + (N + 1);            // N
    f16*   w1h     = (f16*)(cursor + N);           // 256*512
    f16*   w2h     = w1h + (size_t)HID_C * IN_C;   // 64*256
    int*   bsum    = (int*)(w2h + (size_t)OUT_C * HID_C);  // 128
    int*   boff    = bsum + 128;                           // 128

    hipMemsetAsync(cnt, 0, (size_t)N * sizeof(int), stream);

    k_count<<<(E + 255) / 256, 256, 0, stream>>>(ei, cnt, E);
    k_dinv<<<(N + 255) / 256, 256, 0, stream>>>(cnt, dinv, N);
    k_scan1<<<G, 256, 0, stream>>>(cnt, bsum, N);
    k_scan2<<<1, 128, 0, stream>>>(bsum, boff, G, row_ptr, N, E);
    k_scan3<<<G, 256, 0, stream>>>(cnt, boff, row_ptr, cursor, N);
    k_fill<<<(E + 255) / 256, 256, 0, stream>>>(ei, dinv, cursor, csr_pack, E);

    k_cast<<<(HID_C * IN_C + 255) / 256, 256, 0, stream>>>(w1, w1h, HID_C * IN_C);
    k_cast<<<(OUT_C * HID_C + 255) / 256, 256, 0, stream>>>(w2, w2h, OUT_C * HID_C);

    k_mlp2<<<(N + 127) / 128, 512, 0, stream>>>(x, w1h, b1, w2h, b2, h016, h16A, N);

    const int pwaves = (N + 7) / 8;                 // 12500 waves
    const int pblocks = (pwaves * 64 + 255) / 256;  // 3125 blocks
    for (int it = 0; it < K_ITERS; ++it) {
        const f16* pin = (it & 1) ? h16B : h16A;
        f16* pout = (it & 1) ? h16A : h16B;
        k_prop16<<<pblocks, 256, 0, stream>>>(pin, h016, pout, dout, row_ptr,
                                              csr_pack, dinv, N,
                                              it == K_ITERS - 1 ? 1 : 0);
    }
}